// Round 3
// baseline (992.999 us; speedup 1.0000x reference)
//
#include <hip/hip_runtime.h>
#include <hip/hip_bf16.h>

#define T_TOK 2048
#define HID 2048
#define MINTER 1024
#define SINTER 4096
#define NEXP 16

typedef unsigned short u16;
typedef unsigned int u32;
typedef short short8 __attribute__((ext_vector_type(8)));
typedef float f32x4 __attribute__((ext_vector_type(4)));

// s_waitcnt imm encoding (gfx9/CDNA): vmcnt[3:0]|expcnt[6:4]|lgkmcnt[11:8]|vmcnt[5:4]@[15:14]
#define WAITCNT_VM8 0x0F78   // vmcnt<=8, lgkm/exp unconstrained
#define WAITCNT_VM0 0x0F70   // vmcnt<=0

__device__ __forceinline__ u16 f2bf(float f) {
    union { float f; unsigned u; } v; v.f = f;
    unsigned u = v.u;
    unsigned r = (u + 0x7FFFu + ((u >> 16) & 1u)) >> 16;
    return (u16)r;
}

// async global->LDS, 16B per lane; LDS dest is wave-uniform base (+lane*16)
__device__ __forceinline__ void gload16(const void* g, void* s) {
    __builtin_amdgcn_global_load_lds(
        (const __attribute__((address_space(1))) u32*)g,
        (__attribute__((address_space(3))) u32*)s, 16, 0, 0);
}

// ---------------- router (+ fused x fp32->bf16 cvt) ----------------
__global__ __launch_bounds__(256) void router_kernel(
    const float* __restrict__ x, const float* __restrict__ rw, const float* __restrict__ ebias,
    u16* __restrict__ xbf,
    int* __restrict__ counts, int* __restrict__ bid, float* __restrict__ bw)
{
    int t = blockIdx.x;
    int tid = threadIdx.x;
    const float* xp = x + (size_t)t * HID;

    // fused cvt: this token's row -> bf16 (contiguous 8 floats/thread)
    {
        const float4* x4 = (const float4*)xp;
        float4 v0 = x4[tid * 2], v1 = x4[tid * 2 + 1];
        ushort4 o0, o1;
        o0.x = f2bf(v0.x); o0.y = f2bf(v0.y); o0.z = f2bf(v0.z); o0.w = f2bf(v0.w);
        o1.x = f2bf(v1.x); o1.y = f2bf(v1.y); o1.z = f2bf(v1.z); o1.w = f2bf(v1.w);
        ushort4* xo = (ushort4*)(xbf + (size_t)t * HID);
        xo[tid * 2] = o0; xo[tid * 2 + 1] = o1;
    }

    int e = tid >> 4, j = tid & 15;
    const float* wp = rw + (size_t)e * HID;
    float sum = 0.f;
    #pragma unroll 4
    for (int h = j; h < HID; h += 16) sum += xp[h] * wp[h];
    sum += __shfl_xor(sum, 8);
    sum += __shfl_xor(sum, 4);
    sum += __shfl_xor(sum, 2);
    sum += __shfl_xor(sum, 1);
    __shared__ float sc[NEXP];
    if (j == 0) sc[e] = 1.f / (1.f + expf(-sum));
    __syncthreads();
    if (tid == 0) {
        float s[NEXP];
        #pragma unroll
        for (int i = 0; i < NEXP; i++) s[i] = sc[i] + ebias[i];
        float gs[4];
        #pragma unroll
        for (int g = 0; g < 4; g++) {
            float a = s[4*g], b = s[4*g+1], c = s[4*g+2], d = s[4*g+3];
            float hi1 = fmaxf(a,b), lo1 = fminf(a,b);
            float hi2 = fmaxf(c,d), lo2 = fminf(c,d);
            float mx = fmaxf(hi1, hi2);
            float se = fmaxf(fminf(hi1, hi2), fmaxf(lo1, lo2));
            gs[g] = mx + se;
        }
        int g0 = 0;
        for (int g = 1; g < 4; g++) if (gs[g] > gs[g0]) g0 = g;
        int g1 = -1;
        for (int g = 0; g < 4; g++) { if (g == g0) continue; if (g1 < 0 || gs[g] > gs[g1]) g1 = g; }
        int e0 = -1, e1 = -1;
        for (int i = 0; i < NEXP; i++) {
            int g = i >> 2;
            if (g != g0 && g != g1) continue;
            if (e0 < 0 || s[i] > s[e0]) e0 = i;
        }
        for (int i = 0; i < NEXP; i++) {
            int g = i >> 2;
            if (g != g0 && g != g1) continue;
            if (i == e0) continue;
            if (e1 < 0 || s[i] > s[e1]) e1 = i;
        }
        float w0 = sc[e0], w1 = sc[e1];
        float inv = 1.f / (w0 + w1 + 1e-20f);
        w0 *= inv; w1 *= inv;
        int p0 = atomicAdd(&counts[e0], 1);
        bid[e0 * T_TOK + p0] = t * 2;
        bw [e0 * T_TOK + p0] = w0;
        int p1 = atomicAdd(&counts[e1], 1);
        bid[e1 * T_TOK + p1] = t * 2 + 1;
        bw [e1 * T_TOK + p1] = w1;
    }
}

// ---------------- merged [Z][K][N] fp32 -> [Z][N][K] bf16 transposes ----------------
__global__ __launch_bounds__(256) void transpose_all_kernel(
    const float* __restrict__ su, const float* __restrict__ sd,
    const float* __restrict__ wu, const float* __restrict__ wd,
    u16* __restrict__ suT, u16* __restrict__ sdT,
    u16* __restrict__ wuT, u16* __restrict__ wdT)
{
    __shared__ float t[64][65];
    int b = blockIdx.x;
    const float* in; u16* outp; int K, N, kt, nt;
    if (b < 2048) {                       // su: K=2048,N=4096, 32x64 tiles
        in = su; outp = suT; K = 2048; N = 4096; kt = b & 31; nt = b >> 5;
    } else if (b < 4096) {                // sd: K=4096,N=2048, 64x32 tiles
        int r = b - 2048;
        in = sd; outp = sdT; K = 4096; N = 2048; kt = r & 63; nt = r >> 6;
    } else if (b < 12288) {               // wu: z=16, K=2048,N=1024, 32x16 tiles
        int r = b - 4096; int z = r >> 9; int q = r & 511;
        in = wu + (size_t)z * HID * MINTER; outp = wuT + (size_t)z * HID * MINTER;
        K = 2048; N = 1024; kt = q & 31; nt = q >> 5;
    } else {                              // wd: z=16, K=1024,N=2048, 16x32 tiles
        int r = b - 12288; int z = r >> 9; int q = r & 511;
        in = wd + (size_t)z * HID * MINTER; outp = wdT + (size_t)z * HID * MINTER;
        K = 1024; N = 2048; kt = q & 15; nt = q >> 4;
    }
    int k0 = kt * 64, n0 = nt * 64;
    int tid = threadIdx.x;
    int r = tid >> 4, c4 = (tid & 15) * 4;
    #pragma unroll
    for (int i = 0; i < 4; i++) {
        float4 v = *(const float4*)&in[(size_t)(k0 + r + 16*i) * N + n0 + c4];
        t[r + 16*i][c4]     = v.x;
        t[r + 16*i][c4 + 1] = v.y;
        t[r + 16*i][c4 + 2] = v.z;
        t[r + 16*i][c4 + 3] = v.w;
    }
    __syncthreads();
    #pragma unroll
    for (int i = 0; i < 4; i++) {
        int n = r + 16*i;
        ushort4 o;
        o.x = f2bf(t[c4 + 0][n]);
        o.y = f2bf(t[c4 + 1][n]);
        o.z = f2bf(t[c4 + 2][n]);
        o.w = f2bf(t[c4 + 3][n]);
        *(ushort4*)&outp[(size_t)(n0 + n) * K + k0 + c4] = o;
    }
}

// =================== fused UP dispatch (double-buffered pipeline) ===================
// blocks [0,512):   shared-up  : hsh[T,S]  = relu2(xbf @ suT^T)       (bf16)
// blocks [512,...): routed-up  : act[tk,I] = relu2(xbf[t] @ wuT^T)*w  (bf16)
__global__ __launch_bounds__(256, 2) void up_kernel(
    const u16* __restrict__ xbf, const u16* __restrict__ suT,
    const u16* __restrict__ wuT, u16* __restrict__ hsh, u16* __restrict__ act,
    const int* __restrict__ counts, const int* __restrict__ bid,
    const float* __restrict__ bw)
{
    __shared__ alignas(16) u16 As[2][128 * 64];
    __shared__ alignas(16) u16 Bs[2][128 * 64];
    __shared__ int   idsL[128];
    __shared__ float wL[128];

    int b = blockIdx.x;
    int tid = threadIdx.x;
    bool routed = (b >= 512);
    int e = 0, mblk, nblk, M = T_TOK;
    const u16* BT;
    if (!routed) { mblk = b & 15; nblk = b >> 4; BT = suT; }
    else {
        int rb = b - 512; e = rb >> 7; int rem = rb & 127;
        mblk = rem & 15; nblk = rem >> 4;
        M = counts[e];
        if (mblk * 128 >= M) return;
        BT = wuT + (size_t)e * MINTER * HID;
    }
    int m0 = mblk * 128, n0 = nblk * 128;

    if (routed) {
        if (tid < 128) {
            int p = m0 + tid; if (p >= M) p = M - 1;
            idsL[tid] = bid[e * T_TOK + p];
            wL[tid]   = bw [e * T_TOK + p];
        }
        __syncthreads();
    }

    int lane = tid & 63, wid = tid >> 6;
    int rsub = lane >> 3, kseg = (lane & 7) * 8;

    const u16* aG[4]; const u16* bG[4];
    #pragma unroll
    for (int i = 0; i < 4; i++) {
        int rr = wid * 32 + i * 8 + rsub;
        size_t ar = routed ? (size_t)(idsL[rr] >> 1) : (size_t)(m0 + rr);
        aG[i] = xbf + ar * HID + kseg;
        bG[i] = BT + (size_t)(n0 + rr) * HID + kseg;
    }

    f32x4 acc[4][4] = {};
    int wm = (wid & 1) * 64, wn = (wid >> 1) * 64;
    int lrow = lane & 15, lq = lane >> 4;

    const int STEPS = HID / 64;   // 32
    // prefetch step 0
    #pragma unroll
    for (int i = 0; i < 4; i++) {
        gload16(aG[i], &As[0][(wid * 32 + i * 8) * 64]);
        gload16(bG[i], &Bs[0][(wid * 32 + i * 8) * 64]);
    }
    for (int s = 0; s < STEPS; s++) {
        int cur = s & 1;
        if (s + 1 < STEPS) {
            int kk = (s + 1) * 64;
            int nb = (s + 1) & 1;
            #pragma unroll
            for (int i = 0; i < 4; i++) {
                gload16(aG[i] + kk, &As[nb][(wid * 32 + i * 8) * 64]);
                gload16(bG[i] + kk, &Bs[nb][(wid * 32 + i * 8) * 64]);
            }
            __builtin_amdgcn_s_waitcnt(WAITCNT_VM8);
        } else {
            __builtin_amdgcn_s_waitcnt(WAITCNT_VM0);
        }
        __builtin_amdgcn_s_barrier();
        #pragma unroll
        for (int kc = 0; kc < 64; kc += 32) {
            short8 af[4], bf2[4];
            #pragma unroll
            for (int im = 0; im < 4; im++)
                af[im] = *(const short8*)&As[cur][(wm + im*16 + lrow) * 64 + kc + lq * 8];
            #pragma unroll
            for (int in = 0; in < 4; in++)
                bf2[in] = *(const short8*)&Bs[cur][(wn + in*16 + lrow) * 64 + kc + lq * 8];
            #pragma unroll
            for (int im = 0; im < 4; im++)
                #pragma unroll
                for (int in = 0; in < 4; in++)
                    acc[im][in] = __builtin_amdgcn_mfma_f32_16x16x32_bf16(
                        af[im], bf2[in], acc[im][in], 0, 0, 0);
        }
        __builtin_amdgcn_s_barrier();
    }

    #pragma unroll
    for (int im = 0; im < 4; im++) {
        #pragma unroll
        for (int in = 0; in < 4; in++) {
            int ncol = n0 + wn + in*16 + lrow;
            #pragma unroll
            for (int r = 0; r < 4; r++) {
                int mrow = wm + im*16 + lq*4 + r;
                float v = acc[im][in][r];
                float rl = v > 0.f ? v * v : 0.f;
                if (!routed) {
                    hsh[(size_t)(m0 + mrow) * SINTER + ncol] = f2bf(rl);
                } else {
                    if (m0 + mrow < M) {
                        int tk = idsL[mrow];
                        act[(size_t)tk * MINTER + ncol] = f2bf(rl * wL[mrow]);
                    }
                }
            }
        }
    }
}

// =================== fused DOWN dispatch (double-buffered, atomic epilogue) ==========
// blocks [0,256):   shared-down: out[t][h]  += hsh @ sdT^T    K=SINTER
// blocks [256,...): routed-down: out[tk>>1] += act[tk] @ wdT^T K=MINTER
__global__ __launch_bounds__(256, 2) void down_kernel(
    const u16* __restrict__ hsh, const u16* __restrict__ sdT,
    const u16* __restrict__ act, const u16* __restrict__ wdT,
    float* __restrict__ out,
    const int* __restrict__ counts, const int* __restrict__ bid)
{
    __shared__ alignas(16) u16 As[2][128 * 64];
    __shared__ alignas(16) u16 Bs[2][128 * 64];
    __shared__ int idsL[128];

    int b = blockIdx.x;
    int tid = threadIdx.x;
    bool routed = (b >= 256);
    int e = 0, mblk, nblk, M = T_TOK, K, ldA;
    const u16* A; const u16* BT;
    if (!routed) {
        mblk = b & 15; nblk = b >> 4;
        A = hsh; ldA = SINTER; K = SINTER; BT = sdT;
    } else {
        int rb = b - 256; e = rb >> 8; int rem = rb & 255;
        mblk = rem & 15; nblk = rem >> 4;
        M = counts[e];
        if (mblk * 128 >= M) return;
        A = act; ldA = MINTER; K = MINTER;
        BT = wdT + (size_t)e * HID * MINTER;
    }
    int m0 = mblk * 128, n0 = nblk * 128;

    if (routed) {
        if (tid < 128) {
            int p = m0 + tid; if (p >= M) p = M - 1;
            idsL[tid] = bid[e * T_TOK + p];
        }
        __syncthreads();
    }

    int lane = tid & 63, wid = tid >> 6;
    int rsub = lane >> 3, kseg = (lane & 7) * 8;

    const u16* aG[4]; const u16* bG[4];
    #pragma unroll
    for (int i = 0; i < 4; i++) {
        int rr = wid * 32 + i * 8 + rsub;
        size_t ar = routed ? (size_t)idsL[rr] : (size_t)(m0 + rr);
        aG[i] = A + ar * (size_t)ldA + kseg;
        bG[i] = BT + (size_t)(n0 + rr) * K + kseg;
    }

    f32x4 acc[4][4] = {};
    int wm = (wid & 1) * 64, wn = (wid >> 1) * 64;
    int lrow = lane & 15, lq = lane >> 4;

    int steps = K >> 6;
    #pragma unroll
    for (int i = 0; i < 4; i++) {
        gload16(aG[i], &As[0][(wid * 32 + i * 8) * 64]);
        gload16(bG[i], &Bs[0][(wid * 32 + i * 8) * 64]);
    }
    for (int s = 0; s < steps; s++) {
        int cur = s & 1;
        if (s + 1 < steps) {
            int kk = (s + 1) * 64;
            int nb = (s + 1) & 1;
            #pragma unroll
            for (int i = 0; i < 4; i++) {
                gload16(aG[i] + kk, &As[nb][(wid * 32 + i * 8) * 64]);
                gload16(bG[i] + kk, &Bs[nb][(wid * 32 + i * 8) * 64]);
            }
            __builtin_amdgcn_s_waitcnt(WAITCNT_VM8);
        } else {
            __builtin_amdgcn_s_waitcnt(WAITCNT_VM0);
        }
        __builtin_amdgcn_s_barrier();
        #pragma unroll
        for (int kc = 0; kc < 64; kc += 32) {
            short8 af[4], bf2[4];
            #pragma unroll
            for (int im = 0; im < 4; im++)
                af[im] = *(const short8*)&As[cur][(wm + im*16 + lrow) * 64 + kc + lq * 8];
            #pragma unroll
            for (int in = 0; in < 4; in++)
                bf2[in] = *(const short8*)&Bs[cur][(wn + in*16 + lrow) * 64 + kc + lq * 8];
            #pragma unroll
            for (int im = 0; im < 4; im++)
                #pragma unroll
                for (int in = 0; in < 4; in++)
                    acc[im][in] = __builtin_amdgcn_mfma_f32_16x16x32_bf16(
                        af[im], bf2[in], acc[im][in], 0, 0, 0);
        }
        __builtin_amdgcn_s_barrier();
    }

    #pragma unroll
    for (int im = 0; im < 4; im++) {
        #pragma unroll
        for (int in = 0; in < 4; in++) {
            int ncol = n0 + wn + in*16 + lrow;
            #pragma unroll
            for (int r = 0; r < 4; r++) {
                int mrow = wm + im*16 + lq*4 + r;
                float v = acc[im][in][r];
                size_t row;
                if (!routed) {
                    row = (size_t)(m0 + mrow);
                } else {
                    if (m0 + mrow >= M) continue;
                    row = (size_t)(idsL[mrow] >> 1);
                }
                atomicAdd(&out[row * HID + ncol], v);
            }
        }
    }
}

extern "C" void kernel_launch(void* const* d_in, const int* in_sizes, int n_in,
                              void* d_out, int out_size, void* d_ws, size_t ws_size,
                              hipStream_t stream) {
    (void)in_sizes; (void)n_in; (void)out_size; (void)ws_size;
    const float* x  = (const float*)d_in[0];
    const float* rw = (const float*)d_in[1];
    const float* eb = (const float*)d_in[2];
    const float* wu = (const float*)d_in[3];
    const float* wd = (const float*)d_in[4];
    const float* su = (const float*)d_in[5];
    const float* sd = (const float*)d_in[6];
    float* out = (float*)d_out;

    char* p = (char*)d_ws;
    u16*  x_bf = (u16*)p;  p += (size_t)T_TOK * HID * 2;            // 8.4 MB
    u16*  suT  = (u16*)p;  p += (size_t)SINTER * HID * 2;           // 16.8 MB
    u16*  sdT  = (u16*)p;  p += (size_t)HID * SINTER * 2;           // 16.8 MB
    u16*  wuT  = (u16*)p;  p += (size_t)NEXP * MINTER * HID * 2;    // 67.1 MB
    u16*  wdT  = (u16*)p;  p += (size_t)NEXP * HID * MINTER * 2;    // 67.1 MB
    u16*  hsh  = (u16*)p;  p += (size_t)T_TOK * SINTER * 2;         // 16.8 MB
    u16*  act  = (u16*)p;  p += (size_t)T_TOK * 2 * MINTER * 2;     // 8.4 MB
    int*   counts = (int*)p; p += 256;
    int*   bid    = (int*)p; p += (size_t)NEXP * T_TOK * 4;
    float* bw     = (float*)p; p += (size_t)NEXP * T_TOK * 4;

    hipMemsetAsync(counts, 0, NEXP * sizeof(int), stream);
    hipMemsetAsync(out, 0, (size_t)T_TOK * HID * sizeof(float), stream);

    router_kernel<<<T_TOK, 256, 0, stream>>>(x, rw, eb, x_bf, counts, bid, bw);

    transpose_all_kernel<<<20480, 256, 0, stream>>>(su, sd, wu, wd, suT, sdT, wuT, wdT);

    up_kernel<<<512 + NEXP * 8 * 16, 256, 0, stream>>>(
        x_bf, suT, wuT, hsh, act, counts, bid, bw);

    down_kernel<<<256 + NEXP * 16 * 16, 256, 0, stream>>>(
        hsh, sdT, act, wdT, out, counts, bid);
}